// Round 2
// baseline (705.218 us; speedup 1.0000x reference)
//
#include <hip/hip_runtime.h>

typedef unsigned short u16;
typedef unsigned int u32;

#define NN 50000
#define NE 640000

// ---- bf16 helpers (bf16 -> f32 exact: shift<<16; f32 -> bf16 RNE) ----
__device__ __forceinline__ float bfl(u32 u) { return __uint_as_float(u << 16); }
__device__ __forceinline__ float bfh(u32 u) { return __uint_as_float(u & 0xffff0000u); }
__device__ __forceinline__ float bf1(u16 v) { return __uint_as_float(((u32)v) << 16); }
__device__ __forceinline__ u16 f2bf(float f) {
  u32 u = __float_as_uint(f);
  u32 r = (u + 0x7fffu + ((u >> 16) & 1u)) >> 16;
  return (u16)r;
}

// ---------------- dtype probe ----------------
// flags[0] = 1 if float tensors are f32 (else bf16)
// flags[1] = 1 if edge_index is int64 words (else int32)
__global__ void probe_kernel(const u16* __restrict__ x, const int* __restrict__ ei,
                             int* __restrict__ flags) {
  __shared__ int s_f32, s_i32;
  if (threadIdx.x == 0) { s_f32 = 0; s_i32 = 0; }
  __syncthreads();
  int lf = 0, li = 0;
  for (int i = threadIdx.x; i < 8192; i += 256) {
    float v = bf1(x[i]);
    if (!(fabsf(v) < 1e8f)) lf = 1;      // catches huge AND NaN bit patterns
    if (ei[2 * i + 1] != 0) li = 1;      // int32 data has nonzero odd words
  }
  if (lf) s_f32 = 1;
  if (li) s_i32 = 1;
  __syncthreads();
  if (threadIdx.x == 0) {
    flags[0] = s_f32;
    flags[1] = s_i32 ? 0 : 1;
  }
}

// ---------------- CSR build ----------------
__device__ __forceinline__ int edge_val(const int* __restrict__ w, long j, int i64) {
  return i64 ? w[2 * j] : w[j];
}

__global__ void count_kernel(const int* __restrict__ ei, const int* __restrict__ flags,
                             int* __restrict__ cnt, int E) {
  int e = blockIdx.x * blockDim.x + threadIdx.x;
  if (e >= E) return;
  int d = edge_val(ei, (long)E + e, flags[1]);
  if ((u32)d < (u32)NN) atomicAdd(&cnt[d], 1);
}

__global__ void scan_local(const int* __restrict__ cnt, int* __restrict__ excl,
                           int* __restrict__ bsum, int n) {
  __shared__ int sd[256];
  int t = threadIdx.x;
  int g = blockIdx.x * 256 + t;
  int v = (g < n) ? cnt[g] : 0;
  sd[t] = v;
  __syncthreads();
  for (int off = 1; off < 256; off <<= 1) {
    int x = (t >= off) ? sd[t - off] : 0;
    __syncthreads();
    sd[t] += x;
    __syncthreads();
  }
  int incl = sd[t];
  if (g < n) excl[g] = incl - v;
  if (t == 255) bsum[blockIdx.x] = incl;
}

__global__ void scan_totals(const int* __restrict__ bsum, int* __restrict__ boff, int nb) {
  __shared__ int sd[256];
  int t = threadIdx.x;
  int v = (t < nb) ? bsum[t] : 0;
  sd[t] = v;
  __syncthreads();
  for (int off = 1; off < 256; off <<= 1) {
    int x = (t >= off) ? sd[t - off] : 0;
    __syncthreads();
    sd[t] += x;
    __syncthreads();
  }
  if (t < nb) boff[t] = sd[t] - v;
}

__global__ void scan_add(const int* __restrict__ excl, const int* __restrict__ boff,
                         const int* __restrict__ cnt, int* __restrict__ rowptr,
                         int* __restrict__ fillp, int n) {
  int g = blockIdx.x * 256 + threadIdx.x;
  if (g < n) {
    int e2 = excl[g] + boff[blockIdx.x];
    rowptr[g] = e2;
    fillp[g] = e2;
    if (g == n - 1) rowptr[n] = e2 + cnt[g];
  }
}

__global__ void fill_kernel(const int* __restrict__ ei, const int* __restrict__ flags,
                            int* __restrict__ fillp, int* __restrict__ col, int E) {
  int e = blockIdx.x * blockDim.x + threadIdx.x;
  if (e >= E) return;
  int i64 = flags[1];
  int s = edge_val(ei, (long)e, i64);
  int d = edge_val(ei, (long)E + e, i64);
  if ((u32)d >= (u32)NN) return;
  int p = atomicAdd(&fillp[d], 1);
  col[p] = ((u32)s < (u32)NN) ? s : 0;
}

// ---------------- GEMM: Y{a,b,c}[n][j] = sum_k X[n][k] * W{a,b,c}[k][j] (+bias on c) ----
// K=128 fixed. blockIdx.y selects weight, blockIdx.z selects 128-col tile.
// X dtype = (x_follows && flags[0]) ? f32 : bf16. W/bias dtype = flags[0]. Y always bf16.
__global__ __launch_bounds__(256) void gemm3_kernel(
    const void* __restrict__ X,
    const void* __restrict__ Wa, const void* __restrict__ Wb, const void* __restrict__ Wc,
    const void* __restrict__ bias,
    u16* __restrict__ Ya, u16* __restrict__ Yb, u16* __restrict__ Yc,
    const int* __restrict__ flags, int x_follows, int N, int M) {
  const int K = 128, MC = 128, TN = 64;
  __shared__ __align__(16) u16 Xs[TN * K];  // 16 KB
  __shared__ __align__(16) u16 Ws[K * MC];  // 32 KB
  int t = threadIdx.x;
  int n0 = blockIdx.x * TN;
  int c0 = blockIdx.z * MC;
  int F32 = flags[0];
  int F32X = x_follows ? F32 : 0;
  const void* W = (blockIdx.y == 0) ? Wa : ((blockIdx.y == 1) ? Wb : Wc);
  u16* Y = (blockIdx.y == 0) ? Ya : ((blockIdx.y == 1) ? Yb : Yc);

  {
    u32* Xsu = (u32*)Xs;
    if (!F32X) {
      const u32* Xg = (const u32*)X;
      for (int i = t; i < TN * (K / 2); i += 256) {
        int r = i >> 6;
        int n = n0 + r;
        Xsu[i] = (n < N) ? Xg[(size_t)n * (K / 2) + (i & 63)] : 0u;
      }
    } else {
      const float* Xg = (const float*)X;
      for (int i = t; i < TN * (K / 2); i += 256) {
        int r = i >> 6;
        int c2 = (i & 63) * 2;
        int n = n0 + r;
        u32 pk = 0;
        if (n < N) {
          u16 a = f2bf(Xg[(size_t)n * K + c2]);
          u16 b = f2bf(Xg[(size_t)n * K + c2 + 1]);
          pk = (u32)a | ((u32)b << 16);
        }
        Xsu[i] = pk;
      }
    }
    u32* Wsu = (u32*)Ws;
    if (!F32) {
      const u16* Wg = (const u16*)W;
      for (int i = t; i < K * (MC / 2); i += 256) {
        int k = i >> 6;
        int j2 = i & 63;
        Wsu[i] = *(const u32*)(Wg + (size_t)k * M + c0 + j2 * 2);
      }
    } else {
      const float* Wg = (const float*)W;
      for (int i = t; i < K * (MC / 2); i += 256) {
        int k = i >> 6;
        int j2 = (i & 63) * 2;
        u16 a = f2bf(Wg[(size_t)k * M + c0 + j2]);
        u16 b = f2bf(Wg[(size_t)k * M + c0 + j2 + 1]);
        Wsu[i] = (u32)a | ((u32)b << 16);
      }
    }
  }
  __syncthreads();

  int tc = t & 31, tr = t >> 5;
  int j0 = tc * 4, r0 = tr * 8;
  float acc[8][4];
#pragma unroll
  for (int i = 0; i < 8; ++i)
#pragma unroll
    for (int j = 0; j < 4; ++j) acc[i][j] = 0.f;

#pragma unroll 4
  for (int k = 0; k < K; k += 2) {
    uint2 wu0 = *(const uint2*)(Ws + k * MC + j0);
    uint2 wu1 = *(const uint2*)(Ws + (k + 1) * MC + j0);
    float w00 = bfl(wu0.x), w01 = bfh(wu0.x), w02 = bfl(wu0.y), w03 = bfh(wu0.y);
    float w10 = bfl(wu1.x), w11 = bfh(wu1.x), w12 = bfl(wu1.y), w13 = bfh(wu1.y);
#pragma unroll
    for (int i = 0; i < 8; ++i) {
      u32 xu = *(const u32*)(Xs + (r0 + i) * K + k);
      float x0 = bfl(xu), x1 = bfh(xu);
      acc[i][0] += x0 * w00 + x1 * w10;
      acc[i][1] += x0 * w01 + x1 * w11;
      acc[i][2] += x0 * w02 + x1 * w12;
      acc[i][3] += x0 * w03 + x1 * w13;
    }
  }

  float bv[4] = {0.f, 0.f, 0.f, 0.f};
  if (blockIdx.y == 2) {
#pragma unroll
    for (int i = 0; i < 4; ++i)
      bv[i] = F32 ? ((const float*)bias)[c0 + j0 + i] : bf1(((const u16*)bias)[c0 + j0 + i]);
  }
#pragma unroll
  for (int i = 0; i < 8; ++i) {
    int n = n0 + r0 + i;
    if (n < N) {
      u16 o0 = f2bf(acc[i][0] + bv[0]);
      u16 o1 = f2bf(acc[i][1] + bv[1]);
      u16 o2 = f2bf(acc[i][2] + bv[2]);
      u16 o3 = f2bf(acc[i][3] + bv[3]);
      uint2 pk;
      pk.x = (u32)o0 | ((u32)o1 << 16);
      pk.y = (u32)o2 | ((u32)o3 << 16);
      *(uint2*)(Y + (size_t)n * M + c0 + j0) = pk;
    }
  }
}

// ---------------- GATv2 aggregation: one wave per dst node, online softmax ----------------
// xl/xr/res always bf16 (internal). att dtype = flags[0]. out dtype = out_follows? flags[0] : bf16.
template <int F, bool ELU>
__global__ __launch_bounds__(256) void gat_agg_kernel(
    const u16* __restrict__ xl, const u16* __restrict__ xr, const u16* __restrict__ res,
    const void* __restrict__ att, const int* __restrict__ rowptr, const int* __restrict__ col,
    void* __restrict__ out, const int* __restrict__ flags, int out_follows, int N) {
  constexpr int EPL = F / 64;
  int lane = threadIdx.x & 63;
  int node = blockIdx.x * 4 + (threadIdx.x >> 6);
  if (node >= N) return;
  int F32 = flags[0];
  int OF32 = out_follows ? F32 : 0;
  int base = lane * EPL;
  float xrv[EPL], attv[EPL], acc[EPL];
#pragma unroll
  for (int e = 0; e < EPL; ++e) {
    xrv[e] = bf1(xr[(size_t)node * F + base + e]);
    attv[e] = F32 ? ((const float*)att)[base + e] : bf1(((const u16*)att)[base + e]);
    acc[e] = 0.f;
  }
  float m = -1e30f, l = 0.f;
  int beg = rowptr[node], end = rowptr[node + 1];
  for (int j = beg; j < end; ++j) {
    int s = col[j];
    if ((u32)s >= (u32)N) continue;
    float xlv[EPL];
    if constexpr (EPL == 2) {
      u32 u = *(const u32*)(xl + (size_t)s * F + base);
      xlv[0] = bfl(u);
      xlv[1] = bfh(u);
    } else {
      uint2 u = *(const uint2*)(xl + (size_t)s * F + base);
      xlv[0] = bfl(u.x);
      xlv[1] = bfh(u.x);
      xlv[2] = bfl(u.y);
      xlv[3] = bfh(u.y);
    }
    float p = 0.f;
#pragma unroll
    for (int e = 0; e < EPL; ++e) {
      float h = xlv[e] + xrv[e];
      float lr = (h > 0.f) ? h : 0.2f * h;
      p = fmaf(attv[e], lr, p);
    }
#pragma unroll
    for (int off = 32; off > 0; off >>= 1) p += __shfl_xor(p, off, 64);
    float mn = fmaxf(m, p);
    float scl = __expf(m - mn);
    float w = __expf(p - mn);
    l = l * scl + w;
#pragma unroll
    for (int e = 0; e < EPL; ++e) acc[e] = acc[e] * scl + w * xlv[e];
    m = mn;
  }
  float inv = 1.f / (l + 1e-16f);
  float ov[EPL];
#pragma unroll
  for (int e = 0; e < EPL; ++e) {
    float o = fmaf(acc[e], inv, bf1(res[(size_t)node * F + base + e]));
    if (ELU) o = (o > 0.f) ? o : (__expf(o) - 1.f);
    ov[e] = o;
  }
  if (OF32) {
    float* of = (float*)out;
#pragma unroll
    for (int e = 0; e < EPL; ++e) of[(size_t)node * F + base + e] = ov[e];
  } else {
    u16* o16 = (u16*)out;
    if constexpr (EPL == 2) {
      u32 pk = (u32)f2bf(ov[0]) | ((u32)f2bf(ov[1]) << 16);
      *(u32*)(o16 + (size_t)node * F + base) = pk;
    } else {
      uint2 pk;
      pk.x = (u32)f2bf(ov[0]) | ((u32)f2bf(ov[1]) << 16);
      pk.y = (u32)f2bf(ov[2]) | ((u32)f2bf(ov[3]) << 16);
      *(uint2*)(o16 + (size_t)node * F + base) = pk;
    }
  }
}

extern "C" void kernel_launch(void* const* d_in, const int* in_sizes, int n_in,
                              void* d_out, int out_size, void* d_ws, size_t ws_size,
                              hipStream_t stream) {
  const u16* x16 = (const u16*)d_in[0];
  const int* ei = (const int*)d_in[1];
  const int N = NN, E = NE;

  char* ws = (char*)d_ws;
  size_t off = 0;
  auto alloc = [&](size_t bytes) -> void* {
    void* p = (void*)(ws + off);
    off += (bytes + 255) & ~(size_t)255;
    return p;
  };
  int* flags = (int*)alloc(2 * 4);
  int* cnt = (int*)alloc((size_t)N * 4);
  int* rowptr = (int*)alloc((size_t)(N + 1) * 4);
  int* fillp = (int*)alloc((size_t)N * 4);
  int* colb = (int*)alloc((size_t)E * 4);
  int* excl = (int*)alloc((size_t)N * 4);
  int* bsum = (int*)alloc(256 * 4);
  int* boff = (int*)alloc(256 * 4);
  // overlaid float buffers (bf16): buf1/buf2/buf3 serve layer1 (first half) then layer2
  u16* buf1 = (u16*)alloc((size_t)N * 256 * 2);  // xl1 / xl2
  u16* buf2 = (u16*)alloc((size_t)N * 256 * 2);  // xr1 / xr2
  u16* buf3 = (u16*)alloc((size_t)N * 256 * 2);  // res1 / res2
  u16* h1 = (u16*)alloc((size_t)N * 128 * 2);
  (void)ws_size; (void)n_in; (void)in_sizes; (void)out_size;

  u16* xl1 = buf1; u16* xr1 = buf2; u16* res1 = buf3;
  u16* xl2 = buf1; u16* xr2 = buf2; u16* res2 = buf3;

  int nb = (N + 255) / 256;  // 196

  probe_kernel<<<1, 256, 0, stream>>>(x16, ei, flags);
  hipMemsetAsync(cnt, 0, (size_t)N * 4, stream);
  count_kernel<<<(E + 255) / 256, 256, 0, stream>>>(ei, flags, cnt, E);
  scan_local<<<nb, 256, 0, stream>>>(cnt, excl, bsum, N);
  scan_totals<<<1, 256, 0, stream>>>(bsum, boff, nb);
  scan_add<<<nb, 256, 0, stream>>>(excl, boff, cnt, rowptr, fillp, N);
  fill_kernel<<<(E + 255) / 256, 256, 0, stream>>>(ei, flags, fillp, colb, E);

  int gx = (N + 63) / 64;  // 782
  // Layer 1: 128 -> 128
  gemm3_kernel<<<dim3(gx, 3, 1), 256, 0, stream>>>(
      d_in[0], d_in[2], d_in[3], d_in[5], d_in[6], xl1, xr1, res1, flags, 1, N, 128);
  gat_agg_kernel<128, true><<<(N + 3) / 4, 256, 0, stream>>>(
      xl1, xr1, res1, d_in[4], rowptr, colb, h1, flags, 0, N);
  // Layer 2: 128 -> 256
  gemm3_kernel<<<dim3(gx, 3, 2), 256, 0, stream>>>(
      h1, d_in[7], d_in[8], d_in[10], d_in[11], xl2, xr2, res2, flags, 0, N, 256);
  gat_agg_kernel<256, false><<<(N + 3) / 4, 256, 0, stream>>>(
      xl2, xr2, res2, d_in[9], rowptr, colb, d_out, flags, 1, N);
}

// Round 3
// 439.211 us; speedup vs baseline: 1.6056x; 1.6056x over previous
//
#include <hip/hip_runtime.h>

typedef unsigned short u16;
typedef unsigned int u32;
typedef __attribute__((ext_vector_type(8))) short bf16x8;
typedef __attribute__((ext_vector_type(4))) float f32x4;

#define NN 50000
#define NE 640000

// ---- bf16 helpers (bf16 -> f32 exact: shift<<16; f32 -> bf16 RNE) ----
__device__ __forceinline__ float bfl(u32 u) { return __uint_as_float(u << 16); }
__device__ __forceinline__ float bfh(u32 u) { return __uint_as_float(u & 0xffff0000u); }
__device__ __forceinline__ float bf1(u16 v) { return __uint_as_float(((u32)v) << 16); }
__device__ __forceinline__ u16 f2bf(float f) {
  u32 u = __float_as_uint(f);
  u32 r = (u + 0x7fffu + ((u >> 16) & 1u)) >> 16;
  return (u16)r;
}

// ---------------- dtype probe ----------------
__global__ void probe_kernel(const u16* __restrict__ x, const int* __restrict__ ei,
                             int* __restrict__ flags) {
  __shared__ int s_f32, s_i32;
  if (threadIdx.x == 0) { s_f32 = 0; s_i32 = 0; }
  __syncthreads();
  int lf = 0, li = 0;
  for (int i = threadIdx.x; i < 8192; i += 256) {
    float v = bf1(x[i]);
    if (!(fabsf(v) < 1e8f)) lf = 1;
    if (ei[2 * i + 1] != 0) li = 1;
  }
  if (lf) s_f32 = 1;
  if (li) s_i32 = 1;
  __syncthreads();
  if (threadIdx.x == 0) {
    flags[0] = s_f32;
    flags[1] = s_i32 ? 0 : 1;
  }
}

// ---------------- CSR build ----------------
__device__ __forceinline__ int edge_val(const int* __restrict__ w, long j, int i64) {
  return i64 ? w[2 * j] : w[j];
}

__global__ void count_kernel(const int* __restrict__ ei, const int* __restrict__ flags,
                             int* __restrict__ cnt, int E) {
  int e = blockIdx.x * blockDim.x + threadIdx.x;
  if (e >= E) return;
  int d = edge_val(ei, (long)E + e, flags[1]);
  if ((u32)d < (u32)NN) atomicAdd(&cnt[d], 1);
}

__global__ void scan_local(const int* __restrict__ cnt, int* __restrict__ excl,
                           int* __restrict__ bsum, int n) {
  __shared__ int sd[256];
  int t = threadIdx.x;
  int g = blockIdx.x * 256 + t;
  int v = (g < n) ? cnt[g] : 0;
  sd[t] = v;
  __syncthreads();
  for (int off = 1; off < 256; off <<= 1) {
    int x = (t >= off) ? sd[t - off] : 0;
    __syncthreads();
    sd[t] += x;
    __syncthreads();
  }
  int incl = sd[t];
  if (g < n) excl[g] = incl - v;
  if (t == 255) bsum[blockIdx.x] = incl;
}

__global__ void scan_totals(const int* __restrict__ bsum, int* __restrict__ boff, int nb) {
  __shared__ int sd[256];
  int t = threadIdx.x;
  int v = (t < nb) ? bsum[t] : 0;
  sd[t] = v;
  __syncthreads();
  for (int off = 1; off < 256; off <<= 1) {
    int x = (t >= off) ? sd[t - off] : 0;
    __syncthreads();
    sd[t] += x;
    __syncthreads();
  }
  if (t < nb) boff[t] = sd[t] - v;
}

__global__ void scan_add(const int* __restrict__ excl, const int* __restrict__ boff,
                         const int* __restrict__ cnt, int* __restrict__ rowptr,
                         int* __restrict__ fillp, int n) {
  int g = blockIdx.x * 256 + threadIdx.x;
  if (g < n) {
    int e2 = excl[g] + boff[blockIdx.x];
    rowptr[g] = e2;
    fillp[g] = e2;
    if (g == n - 1) rowptr[n] = e2 + cnt[g];
  }
}

__global__ void fill_kernel(const int* __restrict__ ei, const int* __restrict__ flags,
                            int* __restrict__ fillp, int* __restrict__ col, int E) {
  int e = blockIdx.x * blockDim.x + threadIdx.x;
  if (e >= E) return;
  int i64 = flags[1];
  int s = edge_val(ei, (long)e, i64);
  int d = edge_val(ei, (long)E + e, i64);
  if ((u32)d >= (u32)NN) return;
  int p = atomicAdd(&fillp[d], 1);
  col[p] = ((u32)s < (u32)NN) ? s : 0;
}

// ---------------- weight pre-transpose: Wt[j][k] = W[k][j], output bf16 ----------------
__global__ void transpose_w(const void* W0, const void* W1, const void* W2,
                            const void* W3, const void* W4, const void* W5,
                            u16* T0, u16* T1, u16* T2, u16* T3, u16* T4, u16* T5,
                            const int* __restrict__ flags) {
  int y = blockIdx.y;
  int M = (y < 3) ? 128 : 256;
  int flat = blockIdx.x * 256 + threadIdx.x;
  if (flat >= M * 128) return;
  int j = flat >> 7;
  int k = flat & 127;
  const void* W = (y == 0) ? W0 : (y == 1) ? W1 : (y == 2) ? W2 : (y == 3) ? W3 : (y == 4) ? W4 : W5;
  u16* T = (y == 0) ? T0 : (y == 1) ? T1 : (y == 2) ? T2 : (y == 3) ? T3 : (y == 4) ? T4 : T5;
  u16 v;
  if (flags[0])
    v = f2bf(((const float*)W)[(size_t)k * M + j]);
  else
    v = ((const u16*)W)[(size_t)k * M + j];
  T[(size_t)j * 128 + k] = v;
}

// ---------------- MFMA GEMM ----------------
// Y{a,b,c}[n][j] = sum_k X[n][k]*W{a,b,c}[k][j] (+bias on c). K=128.
// 64-row x 128-col C tile per block. Wt = pre-transposed bf16 weights [M][K].
// blockIdx.y selects weight, blockIdx.z selects 128-col tile. Output bf16.
#define LSTR 136  // LDS row stride in elements (16B-aligned, conflict-free)
__global__ __launch_bounds__(256) void gemm3_mfma(
    const void* __restrict__ X,
    const u16* __restrict__ Wta, const u16* __restrict__ Wtb, const u16* __restrict__ Wtc,
    const void* __restrict__ bias,
    u16* __restrict__ Ya, u16* __restrict__ Yb, u16* __restrict__ Yc,
    const int* __restrict__ flags, int x_follows, int N, int M) {
  __shared__ __align__(16) u16 Xs[64 * LSTR];   // 17408 B (reused as Ct in epilogue)
  __shared__ __align__(16) u16 Bs[128 * LSTR];  // 34816 B
  const int K = 128;
  int t = threadIdx.x;
  int lane = t & 63;
  int w = t >> 6;
  int n0g = blockIdx.x * 64;
  int c0 = blockIdx.z * 128;
  int F32X = x_follows ? flags[0] : 0;
  const u16* Wt = (blockIdx.y == 0) ? Wta : ((blockIdx.y == 1) ? Wtb : Wtc);
  u16* Y = (blockIdx.y == 0) ? Ya : ((blockIdx.y == 1) ? Yb : Yc);

  // ---- stage X tile (64 rows x 128 k), bf16 ----
  if (!F32X) {
    const u16* Xg = (const u16*)X;
    for (int it = 0; it < 4; ++it) {
      int i = t + 256 * it;
      int r = i >> 4, c8 = (i & 15) * 8;
      int n = n0g + r;
      uint4 v = make_uint4(0, 0, 0, 0);
      if (n < N) v = *(const uint4*)(Xg + (size_t)n * K + c8);
      *(uint4*)(Xs + r * LSTR + c8) = v;
    }
  } else {
    const float* Xg = (const float*)X;
    for (int it = 0; it < 4; ++it) {
      int i = t + 256 * it;
      int r = i >> 4, c8 = (i & 15) * 8;
      int n = n0g + r;
      uint4 pk = make_uint4(0, 0, 0, 0);
      if (n < N) {
        float4 f0 = *(const float4*)(Xg + (size_t)n * K + c8);
        float4 f1 = *(const float4*)(Xg + (size_t)n * K + c8 + 4);
        pk.x = (u32)f2bf(f0.x) | ((u32)f2bf(f0.y) << 16);
        pk.y = (u32)f2bf(f0.z) | ((u32)f2bf(f0.w) << 16);
        pk.z = (u32)f2bf(f1.x) | ((u32)f2bf(f1.y) << 16);
        pk.w = (u32)f2bf(f1.z) | ((u32)f2bf(f1.w) << 16);
      }
      *(uint4*)(Xs + r * LSTR + c8) = pk;
    }
  }
  // ---- stage W^T tile (128 cols x 128 k), already bf16 ----
  for (int it = 0; it < 8; ++it) {
    int i = t + 256 * it;
    int j = i >> 4, k8 = (i & 15) * 8;
    uint4 v = *(const uint4*)(Wt + (size_t)(c0 + j) * K + k8);
    *(uint4*)(Bs + j * LSTR + k8) = v;
  }
  __syncthreads();

  // ---- MFMA: wave w covers rows m0..m0+31, cols n0..n0+63 of the 64x128 tile ----
  int m0 = (w >> 1) * 32;
  int n0 = (w & 1) * 64;
  int l15 = lane & 15;
  int q8 = (lane >> 4) * 8;
  f32x4 acc[2][4];
#pragma unroll
  for (int i = 0; i < 2; ++i)
#pragma unroll
    for (int j = 0; j < 4; ++j) acc[i][j] = (f32x4){0.f, 0.f, 0.f, 0.f};

#pragma unroll
  for (int kc = 0; kc < 4; ++kc) {
    int ko = kc * 32 + q8;
    bf16x8 a[2], b[4];
#pragma unroll
    for (int i = 0; i < 2; ++i)
      a[i] = *(const bf16x8*)(Xs + (m0 + i * 16 + l15) * LSTR + ko);
#pragma unroll
    for (int j = 0; j < 4; ++j)
      b[j] = *(const bf16x8*)(Bs + (n0 + j * 16 + l15) * LSTR + ko);
#pragma unroll
    for (int i = 0; i < 2; ++i)
#pragma unroll
      for (int j = 0; j < 4; ++j)
        acc[i][j] = __builtin_amdgcn_mfma_f32_16x16x32_bf16(a[i], b[j], acc[i][j], 0, 0, 0);
  }
  __syncthreads();  // all waves done reading Xs/Bs before Ct overwrite

  // ---- bias (only blockIdx.y==2) ----
  float bv[4] = {0.f, 0.f, 0.f, 0.f};
  if (blockIdx.y == 2) {
    int F32 = flags[0];
#pragma unroll
    for (int j = 0; j < 4; ++j) {
      int c = c0 + n0 + j * 16 + l15;
      bv[j] = F32 ? ((const float*)bias)[c] : bf1(((const u16*)bias)[c]);
    }
  }

  // ---- write C to LDS (bf16), then coalesced copy out ----
  u16* Ct = Xs;  // 64 x LSTR
#pragma unroll
  for (int i = 0; i < 2; ++i)
#pragma unroll
    for (int j = 0; j < 4; ++j) {
      int col = n0 + j * 16 + l15;
      int rbase = m0 + i * 16 + (lane >> 4) * 4;
#pragma unroll
      for (int r = 0; r < 4; ++r)
        Ct[(rbase + r) * LSTR + col] = f2bf(acc[i][j][r] + bv[j]);
    }
  __syncthreads();

  for (int it = 0; it < 4; ++it) {
    int i = t + 256 * it;
    int r = i >> 4, c8 = (i & 15) * 8;
    int n = n0g + r;
    if (n < N) {
      uint4 v = *(const uint4*)(Ct + r * LSTR + c8);
      *(uint4*)(Y + (size_t)n * M + c0 + c8) = v;
    }
  }
}

// ---------------- GATv2 aggregation: one wave per dst node, online softmax ----------------
template <int F, bool ELU>
__global__ __launch_bounds__(256) void gat_agg_kernel(
    const u16* __restrict__ xl, const u16* __restrict__ xr, const u16* __restrict__ res,
    const void* __restrict__ att, const int* __restrict__ rowptr, const int* __restrict__ col,
    void* __restrict__ out, const int* __restrict__ flags, int out_follows, int N) {
  constexpr int EPL = F / 64;
  int lane = threadIdx.x & 63;
  int node = blockIdx.x * 4 + (threadIdx.x >> 6);
  if (node >= N) return;
  int F32 = flags[0];
  int OF32 = out_follows ? F32 : 0;
  int base = lane * EPL;
  float xrv[EPL], attv[EPL], acc[EPL];
#pragma unroll
  for (int e = 0; e < EPL; ++e) {
    xrv[e] = bf1(xr[(size_t)node * F + base + e]);
    attv[e] = F32 ? ((const float*)att)[base + e] : bf1(((const u16*)att)[base + e]);
    acc[e] = 0.f;
  }
  float m = -1e30f, l = 0.f;
  int beg = rowptr[node], end = rowptr[node + 1];
  for (int j = beg; j < end; ++j) {
    int s = col[j];
    if ((u32)s >= (u32)N) continue;
    float xlv[EPL];
    if constexpr (EPL == 2) {
      u32 u = *(const u32*)(xl + (size_t)s * F + base);
      xlv[0] = bfl(u);
      xlv[1] = bfh(u);
    } else {
      uint2 u = *(const uint2*)(xl + (size_t)s * F + base);
      xlv[0] = bfl(u.x);
      xlv[1] = bfh(u.x);
      xlv[2] = bfl(u.y);
      xlv[3] = bfh(u.y);
    }
    float p = 0.f;
#pragma unroll
    for (int e = 0; e < EPL; ++e) {
      float h = xlv[e] + xrv[e];
      float lr = (h > 0.f) ? h : 0.2f * h;
      p = fmaf(attv[e], lr, p);
    }
#pragma unroll
    for (int off = 32; off > 0; off >>= 1) p += __shfl_xor(p, off, 64);
    float mn = fmaxf(m, p);
    float scl = __expf(m - mn);
    float wgt = __expf(p - mn);
    l = l * scl + wgt;
#pragma unroll
    for (int e = 0; e < EPL; ++e) acc[e] = acc[e] * scl + wgt * xlv[e];
    m = mn;
  }
  float inv = 1.f / (l + 1e-16f);
  float ov[EPL];
#pragma unroll
  for (int e = 0; e < EPL; ++e) {
    float o = fmaf(acc[e], inv, bf1(res[(size_t)node * F + base + e]));
    if (ELU) o = (o > 0.f) ? o : (__expf(o) - 1.f);
    ov[e] = o;
  }
  if (OF32) {
    float* of = (float*)out;
#pragma unroll
    for (int e = 0; e < EPL; ++e) of[(size_t)node * F + base + e] = ov[e];
  } else {
    u16* o16 = (u16*)out;
    if constexpr (EPL == 2) {
      u32 pk = (u32)f2bf(ov[0]) | ((u32)f2bf(ov[1]) << 16);
      *(u32*)(o16 + (size_t)node * F + base) = pk;
    } else {
      uint2 pk;
      pk.x = (u32)f2bf(ov[0]) | ((u32)f2bf(ov[1]) << 16);
      pk.y = (u32)f2bf(ov[2]) | ((u32)f2bf(ov[3]) << 16);
      *(uint2*)(o16 + (size_t)node * F + base) = pk;
    }
  }
}

extern "C" void kernel_launch(void* const* d_in, const int* in_sizes, int n_in,
                              void* d_out, int out_size, void* d_ws, size_t ws_size,
                              hipStream_t stream) {
  const u16* x16 = (const u16*)d_in[0];
  const int* ei = (const int*)d_in[1];
  const int N = NN, E = NE;

  char* ws = (char*)d_ws;
  size_t off = 0;
  auto alloc = [&](size_t bytes) -> void* {
    void* p = (void*)(ws + off);
    off += (bytes + 255) & ~(size_t)255;
    return p;
  };
  int* flags = (int*)alloc(2 * 4);
  int* cnt = (int*)alloc((size_t)N * 4);
  int* rowptr = (int*)alloc((size_t)(N + 1) * 4);
  int* fillp = (int*)alloc((size_t)N * 4);
  int* colb = (int*)alloc((size_t)E * 4);
  int* excl = (int*)alloc((size_t)N * 4);
  int* bsum = (int*)alloc(256 * 4);
  int* boff = (int*)alloc(256 * 4);
  // pre-transposed weights (bf16, [M][K])
  u16* Wt1a = (u16*)alloc((size_t)128 * 128 * 2);
  u16* Wt1b = (u16*)alloc((size_t)128 * 128 * 2);
  u16* Wt1c = (u16*)alloc((size_t)128 * 128 * 2);
  u16* Wt2a = (u16*)alloc((size_t)256 * 128 * 2);
  u16* Wt2b = (u16*)alloc((size_t)256 * 128 * 2);
  u16* Wt2c = (u16*)alloc((size_t)256 * 128 * 2);
  // overlaid activation buffers (bf16)
  u16* buf1 = (u16*)alloc((size_t)N * 256 * 2);  // xl1 / xl2
  u16* buf2 = (u16*)alloc((size_t)N * 256 * 2);  // xr1 / xr2
  u16* buf3 = (u16*)alloc((size_t)N * 256 * 2);  // res1 / res2
  u16* h1 = (u16*)alloc((size_t)N * 128 * 2);
  (void)ws_size; (void)n_in; (void)in_sizes; (void)out_size;

  int nb = (N + 255) / 256;  // 196

  probe_kernel<<<1, 256, 0, stream>>>(x16, ei, flags);
  hipMemsetAsync(cnt, 0, (size_t)N * 4, stream);
  count_kernel<<<(E + 255) / 256, 256, 0, stream>>>(ei, flags, cnt, E);
  scan_local<<<nb, 256, 0, stream>>>(cnt, excl, bsum, N);
  scan_totals<<<1, 256, 0, stream>>>(bsum, boff, nb);
  scan_add<<<nb, 256, 0, stream>>>(excl, boff, cnt, rowptr, fillp, N);
  fill_kernel<<<(E + 255) / 256, 256, 0, stream>>>(ei, flags, fillp, colb, E);
  transpose_w<<<dim3(128, 6), 256, 0, stream>>>(
      d_in[2], d_in[3], d_in[5], d_in[7], d_in[8], d_in[10],
      Wt1a, Wt1b, Wt1c, Wt2a, Wt2b, Wt2c, flags);

  int gx = (N + 63) / 64;  // 782
  // Layer 1: 128 -> 128
  gemm3_mfma<<<dim3(gx, 3, 1), 256, 0, stream>>>(
      d_in[0], Wt1a, Wt1b, Wt1c, d_in[6], buf1, buf2, buf3, flags, 1, N, 128);
  gat_agg_kernel<128, true><<<(N + 3) / 4, 256, 0, stream>>>(
      buf1, buf2, buf3, d_in[4], rowptr, colb, h1, flags, 0, N);
  // Layer 2: 128 -> 256
  gemm3_mfma<<<dim3(gx, 3, 2), 256, 0, stream>>>(
      h1, Wt2a, Wt2b, Wt2c, d_in[11], buf1, buf2, buf3, flags, 0, N, 256);
  gat_agg_kernel<256, false><<<(N + 3) / 4, 256, 0, stream>>>(
      buf1, buf2, buf3, d_in[9], rowptr, colb, d_out, flags, 1, N);
}

// Round 4
// 385.082 us; speedup vs baseline: 1.8313x; 1.1406x over previous
//
#include <hip/hip_runtime.h>

typedef unsigned short u16;
typedef unsigned int u32;
typedef __attribute__((ext_vector_type(8))) short bf16x8;
typedef __attribute__((ext_vector_type(4))) float f32x4;

#define NN 50000
#define NE 640000

// ---- bf16 helpers (bf16 -> f32 exact: shift<<16; f32 -> bf16 RNE) ----
__device__ __forceinline__ float bfl(u32 u) { return __uint_as_float(u << 16); }
__device__ __forceinline__ float bfh(u32 u) { return __uint_as_float(u & 0xffff0000u); }
__device__ __forceinline__ float bf1(u16 v) { return __uint_as_float(((u32)v) << 16); }
__device__ __forceinline__ u16 f2bf(float f) {
  u32 u = __float_as_uint(f);
  u32 r = (u + 0x7fffu + ((u >> 16) & 1u)) >> 16;
  return (u16)r;
}

// ---------------- dtype probe ----------------
__global__ void probe_kernel(const u16* __restrict__ x, const int* __restrict__ ei,
                             int* __restrict__ flags) {
  __shared__ int s_f32, s_i32;
  if (threadIdx.x == 0) { s_f32 = 0; s_i32 = 0; }
  __syncthreads();
  int lf = 0, li = 0;
  for (int i = threadIdx.x; i < 8192; i += 256) {
    float v = bf1(x[i]);
    if (!(fabsf(v) < 1e8f)) lf = 1;
    if (ei[2 * i + 1] != 0) li = 1;
  }
  if (lf) s_f32 = 1;
  if (li) s_i32 = 1;
  __syncthreads();
  if (threadIdx.x == 0) {
    flags[0] = s_f32;
    flags[1] = s_i32 ? 0 : 1;
  }
}

// ---------------- CSR build ----------------
__device__ __forceinline__ int edge_val(const int* __restrict__ w, long j, int i64) {
  return i64 ? w[2 * j] : w[j];
}

__global__ void count_kernel(const int* __restrict__ ei, const int* __restrict__ flags,
                             int* __restrict__ cnt, int E) {
  int e = blockIdx.x * blockDim.x + threadIdx.x;
  if (e >= E) return;
  int d = edge_val(ei, (long)E + e, flags[1]);
  if ((u32)d < (u32)NN) atomicAdd(&cnt[d], 1);
}

__global__ void scan_local(const int* __restrict__ cnt, int* __restrict__ excl,
                           int* __restrict__ bsum, int n) {
  __shared__ int sd[256];
  int t = threadIdx.x;
  int g = blockIdx.x * 256 + t;
  int v = (g < n) ? cnt[g] : 0;
  sd[t] = v;
  __syncthreads();
  for (int off = 1; off < 256; off <<= 1) {
    int x = (t >= off) ? sd[t - off] : 0;
    __syncthreads();
    sd[t] += x;
    __syncthreads();
  }
  int incl = sd[t];
  if (g < n) excl[g] = incl - v;
  if (t == 255) bsum[blockIdx.x] = incl;
}

__global__ void scan_totals(const int* __restrict__ bsum, int* __restrict__ boff, int nb) {
  __shared__ int sd[256];
  int t = threadIdx.x;
  int v = (t < nb) ? bsum[t] : 0;
  sd[t] = v;
  __syncthreads();
  for (int off = 1; off < 256; off <<= 1) {
    int x = (t >= off) ? sd[t - off] : 0;
    __syncthreads();
    sd[t] += x;
    __syncthreads();
  }
  if (t < nb) boff[t] = sd[t] - v;
}

__global__ void scan_add(const int* __restrict__ excl, const int* __restrict__ boff,
                         const int* __restrict__ cnt, int* __restrict__ rowptr,
                         int* __restrict__ fillp, int n) {
  int g = blockIdx.x * 256 + threadIdx.x;
  if (g < n) {
    int e2 = excl[g] + boff[blockIdx.x];
    rowptr[g] = e2;
    fillp[g] = e2;
    if (g == n - 1) rowptr[n] = e2 + cnt[g];
  }
}

__global__ void fill_kernel(const int* __restrict__ ei, const int* __restrict__ flags,
                            int* __restrict__ fillp, int* __restrict__ col, int E) {
  int e = blockIdx.x * blockDim.x + threadIdx.x;
  if (e >= E) return;
  int i64 = flags[1];
  int s = edge_val(ei, (long)e, i64);
  int d = edge_val(ei, (long)E + e, i64);
  if ((u32)d >= (u32)NN) return;
  int p = atomicAdd(&fillp[d], 1);
  col[p] = ((u32)s < (u32)NN) ? s : 0;
}

// ---------------- weight pre-transpose: Wt[j][k] = W[k][j], output bf16 ----------------
__global__ void transpose_w(const void* W0, const void* W1, const void* W2,
                            const void* W3, const void* W4, const void* W5,
                            u16* T0, u16* T1, u16* T2, u16* T3, u16* T4, u16* T5,
                            const int* __restrict__ flags) {
  int y = blockIdx.y;
  int M = (y < 3) ? 128 : 256;
  int flat = blockIdx.x * 256 + threadIdx.x;
  if (flat >= M * 128) return;
  int j = flat >> 7;
  int k = flat & 127;
  const void* W = (y == 0) ? W0 : (y == 1) ? W1 : (y == 2) ? W2 : (y == 3) ? W3 : (y == 4) ? W4 : W5;
  u16* T = (y == 0) ? T0 : (y == 1) ? T1 : (y == 2) ? T2 : (y == 3) ? T3 : (y == 4) ? T4 : T5;
  u16 v;
  if (flags[0])
    v = f2bf(((const float*)W)[(size_t)k * M + j]);
  else
    v = ((const u16*)W)[(size_t)k * M + j];
  T[(size_t)j * 128 + k] = v;
}

// ---------------- MFMA GEMM (unchanged from round 3) ----------------
#define LSTR 136
__global__ __launch_bounds__(256) void gemm3_mfma(
    const void* __restrict__ X,
    const u16* __restrict__ Wta, const u16* __restrict__ Wtb, const u16* __restrict__ Wtc,
    const void* __restrict__ bias,
    u16* __restrict__ Ya, u16* __restrict__ Yb, u16* __restrict__ Yc,
    const int* __restrict__ flags, int x_follows, int N, int M) {
  __shared__ __align__(16) u16 Xs[64 * LSTR];
  __shared__ __align__(16) u16 Bs[128 * LSTR];
  const int K = 128;
  int t = threadIdx.x;
  int lane = t & 63;
  int w = t >> 6;
  int n0g = blockIdx.x * 64;
  int c0 = blockIdx.z * 128;
  int F32X = x_follows ? flags[0] : 0;
  const u16* Wt = (blockIdx.y == 0) ? Wta : ((blockIdx.y == 1) ? Wtb : Wtc);
  u16* Y = (blockIdx.y == 0) ? Ya : ((blockIdx.y == 1) ? Yb : Yc);

  if (!F32X) {
    const u16* Xg = (const u16*)X;
    for (int it = 0; it < 4; ++it) {
      int i = t + 256 * it;
      int r = i >> 4, c8 = (i & 15) * 8;
      int n = n0g + r;
      uint4 v = make_uint4(0, 0, 0, 0);
      if (n < N) v = *(const uint4*)(Xg + (size_t)n * K + c8);
      *(uint4*)(Xs + r * LSTR + c8) = v;
    }
  } else {
    const float* Xg = (const float*)X;
    for (int it = 0; it < 4; ++it) {
      int i = t + 256 * it;
      int r = i >> 4, c8 = (i & 15) * 8;
      int n = n0g + r;
      uint4 pk = make_uint4(0, 0, 0, 0);
      if (n < N) {
        float4 f0 = *(const float4*)(Xg + (size_t)n * K + c8);
        float4 f1 = *(const float4*)(Xg + (size_t)n * K + c8 + 4);
        pk.x = (u32)f2bf(f0.x) | ((u32)f2bf(f0.y) << 16);
        pk.y = (u32)f2bf(f0.z) | ((u32)f2bf(f0.w) << 16);
        pk.z = (u32)f2bf(f1.x) | ((u32)f2bf(f1.y) << 16);
        pk.w = (u32)f2bf(f1.z) | ((u32)f2bf(f1.w) << 16);
      }
      *(uint4*)(Xs + r * LSTR + c8) = pk;
    }
  }
  for (int it = 0; it < 8; ++it) {
    int i = t + 256 * it;
    int j = i >> 4, k8 = (i & 15) * 8;
    uint4 v = *(const uint4*)(Wt + (size_t)(c0 + j) * K + k8);
    *(uint4*)(Bs + j * LSTR + k8) = v;
  }
  __syncthreads();

  int m0 = (w >> 1) * 32;
  int n0 = (w & 1) * 64;
  int l15 = lane & 15;
  int q8 = (lane >> 4) * 8;
  f32x4 acc[2][4];
#pragma unroll
  for (int i = 0; i < 2; ++i)
#pragma unroll
    for (int j = 0; j < 4; ++j) acc[i][j] = (f32x4){0.f, 0.f, 0.f, 0.f};

#pragma unroll
  for (int kc = 0; kc < 4; ++kc) {
    int ko = kc * 32 + q8;
    bf16x8 a[2], b[4];
#pragma unroll
    for (int i = 0; i < 2; ++i)
      a[i] = *(const bf16x8*)(Xs + (m0 + i * 16 + l15) * LSTR + ko);
#pragma unroll
    for (int j = 0; j < 4; ++j)
      b[j] = *(const bf16x8*)(Bs + (n0 + j * 16 + l15) * LSTR + ko);
#pragma unroll
    for (int i = 0; i < 2; ++i)
#pragma unroll
      for (int j = 0; j < 4; ++j)
        acc[i][j] = __builtin_amdgcn_mfma_f32_16x16x32_bf16(a[i], b[j], acc[i][j], 0, 0, 0);
  }
  __syncthreads();

  float bv[4] = {0.f, 0.f, 0.f, 0.f};
  if (blockIdx.y == 2) {
    int F32 = flags[0];
#pragma unroll
    for (int j = 0; j < 4; ++j) {
      int c = c0 + n0 + j * 16 + l15;
      bv[j] = F32 ? ((const float*)bias)[c] : bf1(((const u16*)bias)[c]);
    }
  }

  u16* Ct = Xs;
#pragma unroll
  for (int i = 0; i < 2; ++i)
#pragma unroll
    for (int j = 0; j < 4; ++j) {
      int col = n0 + j * 16 + l15;
      int rbase = m0 + i * 16 + (lane >> 4) * 4;
#pragma unroll
      for (int r = 0; r < 4; ++r)
        Ct[(rbase + r) * LSTR + col] = f2bf(acc[i][j][r] + bv[j]);
    }
  __syncthreads();

  for (int it = 0; it < 4; ++it) {
    int i = t + 256 * it;
    int r = i >> 4, c8 = (i & 15) * 8;
    int n = n0g + r;
    if (n < N) {
      uint4 v = *(const uint4*)(Ct + r * LSTR + c8);
      *(uint4*)(Y + (size_t)n * M + c0 + c8) = v;
    }
  }
}

// ---------------- GATv2 aggregation: half-wave per edge, 2 edges/iter ----------------
// 32 lanes cover all F features of one edge (HEPL = F/32 per lane).
// Wave-uniform branchy online softmax; col preload + 1-deep gather pipeline.
template <int F, bool ELU>
__global__ __launch_bounds__(256) void gat_agg_kernel(
    const u16* __restrict__ xl, const u16* __restrict__ xr, const u16* __restrict__ res,
    const void* __restrict__ att, const int* __restrict__ rowptr, const int* __restrict__ col,
    void* __restrict__ out, const int* __restrict__ flags, int out_follows, int N) {
  constexpr int HEPL = F / 32;  // 4 (F=128) or 8 (F=256)
  int lane = threadIdx.x & 63;
  int half = lane >> 5;
  int hl = lane & 31;
  int node = blockIdx.x * 4 + (threadIdx.x >> 6);
  if (node >= N) return;
  int F32 = flags[0];
  int OF32 = out_follows ? F32 : 0;
  int base = hl * HEPL;

  float xrv[HEPL], attv[HEPL], acc[HEPL];
#pragma unroll
  for (int e = 0; e < HEPL; ++e) {
    xrv[e] = bf1(xr[(size_t)node * F + base + e]);
    attv[e] = F32 ? ((const float*)att)[base + e] : bf1(((const u16*)att)[base + e]);
    acc[e] = 0.f;
  }
  float m = -1e30f, l = 0.f;
  int beg = rowptr[node], end = rowptr[node + 1];

  using VecT = typename std::conditional<HEPL == 4, uint2, uint4>::type;

  for (int cs = beg; cs < end; cs += 64) {
    int n = min(64, end - cs);
    int myc = (cs + lane < end) ? col[cs + lane] : 0;
    int itc = (n + 1) >> 1;
    int j0 = half;
    int c = __shfl(myc, (j0 < n) ? j0 : 0, 64);
    VecT v = *(const VecT*)(xl + (size_t)c * F + base);
    for (int it = 0; it < itc; ++it) {
      VecT cur = v;
      int act = (2 * it + half) < n;
      if (it + 1 < itc) {
        int j2 = 2 * (it + 1) + half;
        int c2 = __shfl(myc, (j2 < n) ? j2 : 0, 64);
        v = *(const VecT*)(xl + (size_t)c2 * F + base);
      }
      float xlv[HEPL];
      if constexpr (HEPL == 4) {
        xlv[0] = bfl(cur.x); xlv[1] = bfh(cur.x);
        xlv[2] = bfl(cur.y); xlv[3] = bfh(cur.y);
      } else {
        xlv[0] = bfl(cur.x); xlv[1] = bfh(cur.x);
        xlv[2] = bfl(cur.y); xlv[3] = bfh(cur.y);
        xlv[4] = bfl(cur.z); xlv[5] = bfh(cur.z);
        xlv[6] = bfl(cur.w); xlv[7] = bfh(cur.w);
      }
      float d = 0.f;
#pragma unroll
      for (int e = 0; e < HEPL; ++e) {
        float h = xlv[e] + xrv[e];
        float lr = (h > 0.f) ? h : 0.2f * h;
        d = fmaf(attv[e], lr, d);
      }
#pragma unroll
      for (int off = 1; off <= 16; off <<= 1) d += __shfl_xor(d, off, 64);
      float pmy = act ? d : -1e30f;
      float pm = fmaxf(pmy, __shfl_xor(pmy, 32, 64));
      if (pm <= m) {
        float w = __expf(pmy - m);  // inactive half: exp(-huge) = 0
        l += w + __shfl_xor(w, 32, 64);
#pragma unroll
        for (int e = 0; e < HEPL; ++e) acc[e] = fmaf(w, xlv[e], acc[e]);
      } else {
        float scl = __expf(m - pm);  // first edge: exp(-huge) = 0
        float w = __expf(pmy - pm);
        l = fmaf(l, scl, w + __shfl_xor(w, 32, 64));
#pragma unroll
        for (int e = 0; e < HEPL; ++e) acc[e] = fmaf(acc[e], scl, w * xlv[e]);
        m = pm;
      }
    }
  }

  // merge halves (lane i and i+32 hold the same features, disjoint edge sets)
#pragma unroll
  for (int e = 0; e < HEPL; ++e) acc[e] += __shfl_xor(acc[e], 32, 64);
  float inv = 1.f / (l + 1e-16f);
  if (half == 0) {
    float ov[HEPL];
#pragma unroll
    for (int e = 0; e < HEPL; ++e) {
      float o = fmaf(acc[e], inv, bf1(res[(size_t)node * F + base + e]));
      if (ELU) o = (o > 0.f) ? o : (__expf(o) - 1.f);
      ov[e] = o;
    }
    if (OF32) {
      float* of = (float*)out;
#pragma unroll
      for (int e = 0; e < HEPL; ++e) of[(size_t)node * F + base + e] = ov[e];
    } else {
      u16* o16 = (u16*)out;
      if constexpr (HEPL == 4) {
        uint2 pk;
        pk.x = (u32)f2bf(ov[0]) | ((u32)f2bf(ov[1]) << 16);
        pk.y = (u32)f2bf(ov[2]) | ((u32)f2bf(ov[3]) << 16);
        *(uint2*)(o16 + (size_t)node * F + base) = pk;
      } else {
        uint4 pk;
        pk.x = (u32)f2bf(ov[0]) | ((u32)f2bf(ov[1]) << 16);
        pk.y = (u32)f2bf(ov[2]) | ((u32)f2bf(ov[3]) << 16);
        pk.z = (u32)f2bf(ov[4]) | ((u32)f2bf(ov[5]) << 16);
        pk.w = (u32)f2bf(ov[6]) | ((u32)f2bf(ov[7]) << 16);
        *(uint4*)(o16 + (size_t)node * F + base) = pk;
      }
    }
  }
}

extern "C" void kernel_launch(void* const* d_in, const int* in_sizes, int n_in,
                              void* d_out, int out_size, void* d_ws, size_t ws_size,
                              hipStream_t stream) {
  const u16* x16 = (const u16*)d_in[0];
  const int* ei = (const int*)d_in[1];
  const int N = NN, E = NE;

  char* ws = (char*)d_ws;
  size_t off = 0;
  auto alloc = [&](size_t bytes) -> void* {
    void* p = (void*)(ws + off);
    off += (bytes + 255) & ~(size_t)255;
    return p;
  };
  int* flags = (int*)alloc(2 * 4);
  int* cnt = (int*)alloc((size_t)N * 4);
  int* rowptr = (int*)alloc((size_t)(N + 1) * 4);
  int* fillp = (int*)alloc((size_t)N * 4);
  int* colb = (int*)alloc((size_t)E * 4);
  int* excl = (int*)alloc((size_t)N * 4);
  int* bsum = (int*)alloc(256 * 4);
  int* boff = (int*)alloc(256 * 4);
  u16* Wt1a = (u16*)alloc((size_t)128 * 128 * 2);
  u16* Wt1b = (u16*)alloc((size_t)128 * 128 * 2);
  u16* Wt1c = (u16*)alloc((size_t)128 * 128 * 2);
  u16* Wt2a = (u16*)alloc((size_t)256 * 128 * 2);
  u16* Wt2b = (u16*)alloc((size_t)256 * 128 * 2);
  u16* Wt2c = (u16*)alloc((size_t)256 * 128 * 2);
  u16* buf1 = (u16*)alloc((size_t)N * 256 * 2);
  u16* buf2 = (u16*)alloc((size_t)N * 256 * 2);
  u16* buf3 = (u16*)alloc((size_t)N * 256 * 2);
  u16* h1 = (u16*)alloc((size_t)N * 128 * 2);
  (void)ws_size; (void)n_in; (void)in_sizes; (void)out_size;

  int nb = (N + 255) / 256;

  probe_kernel<<<1, 256, 0, stream>>>(x16, ei, flags);
  hipMemsetAsync(cnt, 0, (size_t)N * 4, stream);
  count_kernel<<<(E + 255) / 256, 256, 0, stream>>>(ei, flags, cnt, E);
  scan_local<<<nb, 256, 0, stream>>>(cnt, excl, bsum, N);
  scan_totals<<<1, 256, 0, stream>>>(bsum, boff, nb);
  scan_add<<<nb, 256, 0, stream>>>(excl, boff, cnt, rowptr, fillp, N);
  fill_kernel<<<(E + 255) / 256, 256, 0, stream>>>(ei, flags, fillp, colb, E);
  transpose_w<<<dim3(128, 6), 256, 0, stream>>>(
      d_in[2], d_in[3], d_in[5], d_in[7], d_in[8], d_in[10],
      Wt1a, Wt1b, Wt1c, Wt2a, Wt2b, Wt2c, flags);

  int gx = (N + 63) / 64;
  gemm3_mfma<<<dim3(gx, 3, 1), 256, 0, stream>>>(
      d_in[0], Wt1a, Wt1b, Wt1c, d_in[6], buf1, buf2, buf3, flags, 1, N, 128);
  gat_agg_kernel<128, true><<<(N + 3) / 4, 256, 0, stream>>>(
      buf1, buf2, buf3, d_in[4], rowptr, colb, h1, flags, 0, N);
  gemm3_mfma<<<dim3(gx, 3, 2), 256, 0, stream>>>(
      h1, Wt2a, Wt2b, Wt2c, d_in[11], buf1, buf2, buf3, flags, 0, N, 256);
  gat_agg_kernel<256, false><<<(N + 3) / 4, 256, 0, stream>>>(
      buf1, buf2, buf3, d_in[9], rowptr, colb, d_out, flags, 1, N);
}